// Round 9
// baseline (799.744 us; speedup 1.0000x reference)
//
#include <hip/hip_runtime.h>
#include <stdint.h>

// Problem constants (n=1, c=32, h=w=128, p=3)
#define NPT    16384        // points (h*w)
#define KD     288          // c*p*p
#define KE     576          // per-point row: [hi(288) | lo(288)] f16
#define NWIN   9            // 9 merged K-windows of 32 (hi+lo staged together)

typedef _Float16 f16;
typedef __attribute__((ext_vector_type(8))) _Float16 half8;
typedef __attribute__((ext_vector_type(4))) float floatx4;

#define AS1(p) ((const __attribute__((address_space(1))) uint32_t*)(p))
#define AS3(p) ((__attribute__((address_space(3))) uint32_t*)(p))

// -------- patch extraction + fp32->2xf16 split + fused norms/init ------------
__global__ void extract_split_kernel(const float* __restrict__ src,
                                     const float* __restrict__ tgt,
                                     f16* __restrict__ Aext,
                                     f16* __restrict__ Bext,
                                     float* __restrict__ rq,
                                     float* __restrict__ rp,
                                     unsigned long long* __restrict__ best) {
  int tid = blockIdx.x * 256 + threadIdx.x;   // 16384*32 threads
  int point = tid >> 5;
  int c = tid & 31;
  int y = point >> 7, x = point & 127;
  f16* arow = Aext + (size_t)point * KE;
  f16* brow = Bext + (size_t)point * KE;
  double sq = 0.0, sp = 0.0;
#pragma unroll
  for (int dy = 0; dy < 3; ++dy) {
    int yy = y + dy - 1; yy = yy < 0 ? 0 : (yy > 127 ? 127 : yy);
#pragma unroll
    for (int dx = 0; dx < 3; ++dx) {
      int xx = x + dx - 1; xx = xx < 0 ? 0 : (xx > 127 ? 127 : xx);
      int k = c * 9 + dy * 3 + dx;
      int m = (c << 14) + (yy << 7) + xx;
      float v = src[m];
      sq += (double)v * (double)v;
      f16 h = (f16)v;
      arow[k] = h; arow[KD + k] = (f16)(v - (float)h);
      v = tgt[m];
      sp += (double)v * (double)v;
      h = (f16)v;
      brow[k] = h; brow[KD + k] = (f16)(v - (float)h);
    }
  }
  // width-32 reduction over the 32 channels of this point
#pragma unroll
  for (int s = 1; s < 32; s <<= 1) {
    sq += __shfl_xor(sq, s, 32);
    sp += __shfl_xor(sp, s, 32);
  }
  if (c == 0) {
    rq[point] = (float)sq;
    rp[point] = (float)sp;
    best[point] = 0xFFFFFFFFFFFFFFFFULL;
  }
}

// --- MFMA GEMM: merged split-products, cross-window dbuf, 1 barrier/window ---
// LDS tile per buffer: 128 rows x 64 halves (8 slots of 16 B).
// Logical slice s of row r lives at phys slot (s ^ (r & 7)):
//   s in [0,4): hi window octet s;  s in [4,8): lo octet s-4.
// 16x16x32 fragment path (round 7: measured 0 bank conflicts; round 8's
// 32x32 variant hit 3.8e7 conflicts -> reverted).
// Pipeline: stage(k+1 -> other buf) issues right after barrier k and is
// drained at barrier k+1, ~2000 cyc later -> global->LDS latency hidden
// (round 7's back-to-back barriers exposed ~700 cyc drain per window).
// 64 KB LDS -> 2 blocks/CU; no min-waves bound (round 6: forced bound
// spilled the accumulator -> 7.4 GB scratch traffic).
__global__ __launch_bounds__(256)
void gemm_argmin_kernel(const f16* __restrict__ A, const f16* __restrict__ B,
                        const float* __restrict__ rq,
                        unsigned long long* __restrict__ best) {
  __shared__ f16 Ash[2][128 * 64];   // 32 KB
  __shared__ f16 Bsh[2][128 * 64];   // 32 KB

  const int nBase = blockIdx.x * 128;
  const int mBase = blockIdx.y * 128;
  const int t = threadIdx.x;
  const int w = t >> 6;           // wave 0..3
  const int l = t & 63;

  // ---- staging decode: per issue, 64 lanes cover 8 rows x 8 phys slots ----
  const int lr = l >> 3;                 // row within 8-row issue group
  const int lt = l & 7;                  // phys 16B slot
  const int sl = lt ^ (lr & 7);          // logical slice this lane fetches
  const int sColOff = (sl < 4) ? sl * 8 : KD + (sl & 3) * 8;  // + kw*32/window
  const f16* aBase[4];
  const f16* bBase[4];
#pragma unroll
  for (int ig = 0; ig < 4; ++ig) {
    int row = w * 32 + ig * 8 + lr;
    aBase[ig] = A + (size_t)(mBase + row) * KE + sColOff;
    bBase[ig] = B + (size_t)(nBase + row) * KE + sColOff;
  }

  // ---- fragment decode (16x16x32) ----
  const int m16 = l & 15;
  const int q   = l >> 4;                // k-quad
  const int pHi = q ^ (m16 & 7);         // phys slot of hi octet q
  const int pLo = pHi ^ 4;               // phys slot of lo octet q
  const int wRow = (w & 1) * 64;
  const int wCol = (w >> 1) * 64;
  const int aHiOff = m16 * 64 + pHi * 8; // + (wRow + i*16)*64
  const int aLoOff = m16 * 64 + pLo * 8;

  floatx4 acc[4][4] = {};

  // stage window kw into buffer buf (8 issues of 1024 B per wave);
  // kw is a compile-time constant at each unrolled instance.
  auto stage = [&](int kw, int buf) {
#pragma unroll
    for (int ig = 0; ig < 4; ++ig)
      __builtin_amdgcn_global_load_lds(AS1(aBase[ig] + kw * 32),
                                       AS3(&Ash[buf][(w * 32 + ig * 8) * 64]), 16, 0, 0);
#pragma unroll
    for (int ig = 0; ig < 4; ++ig)
      __builtin_amdgcn_global_load_lds(AS1(bBase[ig] + kw * 32),
                                       AS3(&Bsh[buf][(w * 32 + ig * 8) * 64]), 16, 0, 0);
  };

  stage(0, 0);
#pragma unroll
  for (int kw = 0; kw < NWIN; ++kw) {
    const int buf = kw & 1;
    __syncthreads();                 // drains stage(kw); buf^1 reads finished
    if (kw + 1 < NWIN) stage(kw + 1, buf ^ 1);

    // product order for min fragment liveness:
    //   hi.hi (ah,bh) -> hi.lo (ah,bl) -> lo.hi (al,bh)
    half8 ah[4], bh[4];
#pragma unroll
    for (int i = 0; i < 4; ++i)
      ah[i] = *(const half8*)&Ash[buf][(wRow + i * 16) * 64 + aHiOff];
#pragma unroll
    for (int j = 0; j < 4; ++j)
      bh[j] = *(const half8*)&Bsh[buf][(wCol + j * 16) * 64 + aHiOff];
#pragma unroll
    for (int i = 0; i < 4; ++i)
#pragma unroll
      for (int j = 0; j < 4; ++j)
        acc[i][j] = __builtin_amdgcn_mfma_f32_16x16x32_f16(ah[i], bh[j], acc[i][j], 0, 0, 0);

    {
      half8 bl[4];
#pragma unroll
      for (int j = 0; j < 4; ++j)
        bl[j] = *(const half8*)&Bsh[buf][(wCol + j * 16) * 64 + aLoOff];
#pragma unroll
      for (int i = 0; i < 4; ++i)
#pragma unroll
        for (int j = 0; j < 4; ++j)
          acc[i][j] = __builtin_amdgcn_mfma_f32_16x16x32_f16(ah[i], bl[j], acc[i][j], 0, 0, 0);
    }
    {
      half8 al[4];
#pragma unroll
      for (int i = 0; i < 4; ++i)
        al[i] = *(const half8*)&Ash[buf][(wRow + i * 16) * 64 + aLoOff];
#pragma unroll
      for (int i = 0; i < 4; ++i)
#pragma unroll
        for (int j = 0; j < 4; ++j)
          acc[i][j] = __builtin_amdgcn_mfma_f32_16x16x32_f16(al[i], bh[j], acc[i][j], 0, 0, 0);
    }
  }

  // ---- epilogue: f = rq[col] - 2*dot, packed argmin ----
  // C/D layout (16x16): col = lane&15, row = (lane>>4)*4 + reg
  const int colBase = nBase + wCol + m16;
  float rqv[4];
#pragma unroll
  for (int j = 0; j < 4; ++j) rqv[j] = rq[colBase + j * 16];

#pragma unroll
  for (int i = 0; i < 4; ++i) {
    const int rowB = mBase + wRow + i * 16 + q * 4;
#pragma unroll
    for (int r = 0; r < 4; ++r) {
      unsigned long long pk = 0xFFFFFFFFFFFFFFFFULL;
#pragma unroll
      for (int j = 0; j < 4; ++j) {
        float f = fmaf(-2.0f, acc[i][j][r], rqv[j]);
        unsigned int bits = __float_as_uint(f);
        unsigned int key = (bits & 0x80000000u) ? ~bits : (bits | 0x80000000u);
        unsigned long long cand =
            ((unsigned long long)key << 32) | (unsigned)(colBase + j * 16);
        pk = pk < cand ? pk : cand;
      }
#pragma unroll
      for (int sft = 1; sft < 16; sft <<= 1) {
        unsigned long long o = __shfl_xor(pk, sft, 16);
        pk = pk < o ? pk : o;
      }
      if (m16 == 0) atomicMin(best + rowB + r, pk);
    }
  }
}

// ---------------------------- finalize ---------------------------------------
__global__ void finalize_kernel(const unsigned long long* __restrict__ best,
                                const float* __restrict__ rp,
                                float* __restrict__ out) {
  int i = blockIdx.x * 256 + threadIdx.x;
  if (i >= NPT) return;
  unsigned long long v = best[i];
  unsigned int col = (unsigned int)(v & 0xFFFFFFFFu);
  unsigned int key = (unsigned int)(v >> 32);
  unsigned int bits = (key & 0x80000000u) ? (key & 0x7FFFFFFFu) : ~key;
  float fmin = __uint_as_float(bits);
  out[i]           = (float)(col >> 7);   // idy
  out[NPT + i]     = (float)(col & 127);  // idx
  out[2 * NPT + i] = rp[i] + fmin;        // nnd
}

extern "C" void kernel_launch(void* const* d_in, const int* in_sizes, int n_in,
                              void* d_out, int out_size, void* d_ws, size_t ws_size,
                              hipStream_t stream) {
  const float* src = (const float*)d_in[0];  // source_map (1,32,128,128)
  const float* tgt = (const float*)d_in[1];  // target_map (1,32,128,128)
  float* out = (float*)d_out;

  // workspace layout (bytes):
  //   Aext: [0, 18874368)        16384 x 576 f16 (point-major [hi|lo])
  //   Bext: [18874368, 37748736)
  //   rq  : [37748736, 37814272) 16384 fp32 (target-side norms for the f-term)
  //   rp  : [37814272, 37879808)
  //   best: [37879808, 38010880) 16384 u64 packed (key<<32)|col
  char* ws = (char*)d_ws;
  f16* Aext = (f16*)(ws);
  f16* Bext = (f16*)(ws + 18874368);
  float* rq = (float*)(ws + 37748736);
  float* rp = (float*)(ws + 37814272);
  unsigned long long* best = (unsigned long long*)(ws + 37879808);

  extract_split_kernel<<<(NPT * 32) / 256, 256, 0, stream>>>(src, tgt, Aext, Bext,
                                                             rq, rp, best);
  {
    dim3 grid(128, 128);
    gemm_argmin_kernel<<<grid, 256, 0, stream>>>(Aext, Bext, rq, best);
  }
  finalize_kernel<<<NPT / 256, 256, 0, stream>>>(best, rp, out);
}

// Round 10
// 571.779 us; speedup vs baseline: 1.3987x; 1.3987x over previous
//
#include <hip/hip_runtime.h>
#include <stdint.h>

// Problem constants (n=1, c=32, h=w=128, p=3)
#define NPT    16384        // points (h*w)
#define KD     288          // c*p*p
#define KE     576          // per-point row: [hi(288) | lo(288)] f16
#define NWIN   9            // 9 merged K-windows of 32 (hi+lo staged together)

typedef _Float16 f16;
typedef __attribute__((ext_vector_type(8))) _Float16 half8;
typedef __attribute__((ext_vector_type(4))) float floatx4;

#define AS1(p) ((const __attribute__((address_space(1))) uint32_t*)(p))
#define AS3(p) ((__attribute__((address_space(3))) uint32_t*)(p))

// -------- patch extraction + fp32->2xf16 split + fused norms/init ------------
__global__ void extract_split_kernel(const float* __restrict__ src,
                                     const float* __restrict__ tgt,
                                     f16* __restrict__ Aext,
                                     f16* __restrict__ Bext,
                                     float* __restrict__ rq,
                                     float* __restrict__ rp,
                                     unsigned long long* __restrict__ best) {
  int tid = blockIdx.x * 256 + threadIdx.x;   // 16384*32 threads
  int point = tid >> 5;
  int c = tid & 31;
  int y = point >> 7, x = point & 127;
  f16* arow = Aext + (size_t)point * KE;
  f16* brow = Bext + (size_t)point * KE;
  double sq = 0.0, sp = 0.0;
#pragma unroll
  for (int dy = 0; dy < 3; ++dy) {
    int yy = y + dy - 1; yy = yy < 0 ? 0 : (yy > 127 ? 127 : yy);
#pragma unroll
    for (int dx = 0; dx < 3; ++dx) {
      int xx = x + dx - 1; xx = xx < 0 ? 0 : (xx > 127 ? 127 : xx);
      int k = c * 9 + dy * 3 + dx;
      int m = (c << 14) + (yy << 7) + xx;
      float v = src[m];
      sq += (double)v * (double)v;
      f16 h = (f16)v;
      arow[k] = h; arow[KD + k] = (f16)(v - (float)h);
      v = tgt[m];
      sp += (double)v * (double)v;
      h = (f16)v;
      brow[k] = h; brow[KD + k] = (f16)(v - (float)h);
    }
  }
  // width-32 reduction over the 32 channels of this point
#pragma unroll
  for (int s = 1; s < 32; s <<= 1) {
    sq += __shfl_xor(sq, s, 32);
    sp += __shfl_xor(sp, s, 32);
  }
  if (c == 0) {
    rq[point] = (float)sq;
    rp[point] = (float)sp;
    best[point] = 0xFFFFFFFFFFFFFFFFULL;
  }
}

// --- MFMA GEMM: round-7 structure, register-slimmed for 4 blocks/CU ----------
// LDS tile: 128 rows x 64 halves (8 slots of 16 B), single buffer (32 KB).
// Logical slice s of row r lives at phys slot (s ^ (r & 7)):
//   s in [0,4): hi window octet s;  s in [4,8): lo octet s-4.
// Register diet vs round 7 (152 unified regs -> target <=128):
//  * staging via uniform SGPR base (Ab/Bb) + 4 shared 32-bit row offsets
//    (A and B row offsets are identical) instead of 8 pointer pairs.
//  * just-in-time fragment loads: ah+bh resident (32 regs), bl then al
//    streamed one tile at a time -> peak ~36 fragment regs (was 48).
// __launch_bounds__(256, 4): request 128-reg budget -> 4 blocks/CU.
// (Round 6's spill disaster was a 50-reg overshoot; here need ~120.)
__global__ __launch_bounds__(256, 4)
void gemm_argmin_kernel(const f16* __restrict__ A, const f16* __restrict__ B,
                        const float* __restrict__ rq,
                        unsigned long long* __restrict__ best) {
  __shared__ f16 Ash[128 * 64];   // 16 KB
  __shared__ f16 Bsh[128 * 64];   // 16 KB

  const int nBase = blockIdx.x * 128;
  const int mBase = blockIdx.y * 128;
  const f16* Ab = A + (size_t)mBase * KE;   // block-uniform -> SGPR pair
  const f16* Bb = B + (size_t)nBase * KE;   // block-uniform -> SGPR pair
  const int t = threadIdx.x;
  const int w = t >> 6;           // wave 0..3
  const int l = t & 63;

  // ---- staging decode: per issue, 64 lanes cover 8 rows x 8 phys slots ----
  const int lr = l >> 3;                 // row within 8-row issue group
  const int lt = l & 7;                  // phys 16B slot
  const int sl = lt ^ (lr & 7);          // logical slice this lane fetches
  const int sColOff = (sl < 4) ? sl * 8 : KD + (sl & 3) * 8;  // + kw*32/window
  int rowHalf[4];                        // identical for A and B
#pragma unroll
  for (int ig = 0; ig < 4; ++ig)
    rowHalf[ig] = (w * 32 + ig * 8 + lr) * KE + sColOff;

  // ---- fragment decode (16x16x32) ----
  const int m16 = l & 15;
  const int q   = l >> 4;                // k-quad
  const int pHi = q ^ (m16 & 7);         // phys slot of hi octet q
  const int pLo = pHi ^ 4;               // phys slot of lo octet q
  const int wRow = (w & 1) * 64;
  const int wCol = (w >> 1) * 64;
  const int aHiOff = m16 * 64 + pHi * 8; // + (wRow + i*16)*64
  const int aLoOff = m16 * 64 + pLo * 8;

  floatx4 acc[4][4] = {};

#pragma unroll
  for (int kw = 0; kw < NWIN; ++kw) {
    __syncthreads();                     // previous window's reads complete
#pragma unroll
    for (int ig = 0; ig < 4; ++ig)
      __builtin_amdgcn_global_load_lds(AS1(Ab + rowHalf[ig] + kw * 32),
                                       AS3(&Ash[(w * 32 + ig * 8) * 64]), 16, 0, 0);
#pragma unroll
    for (int ig = 0; ig < 4; ++ig)
      __builtin_amdgcn_global_load_lds(AS1(Bb + rowHalf[ig] + kw * 32),
                                       AS3(&Bsh[(w * 32 + ig * 8) * 64]), 16, 0, 0);
    __syncthreads();                     // staging drained (vmcnt0 + barrier)

    // phase 1: hi.hi — ah, bh resident
    half8 ah[4], bh[4];
#pragma unroll
    for (int i = 0; i < 4; ++i)
      ah[i] = *(const half8*)&Ash[(wRow + i * 16) * 64 + aHiOff];
#pragma unroll
    for (int j = 0; j < 4; ++j)
      bh[j] = *(const half8*)&Bsh[(wCol + j * 16) * 64 + aHiOff];
#pragma unroll
    for (int i = 0; i < 4; ++i)
#pragma unroll
      for (int j = 0; j < 4; ++j)
        acc[i][j] = __builtin_amdgcn_mfma_f32_16x16x32_f16(ah[i], bh[j], acc[i][j], 0, 0, 0);

    // phase 2: hi.lo — stream bl one tile at a time (peak liveness ~36)
#pragma unroll
    for (int j = 0; j < 4; ++j) {
      half8 bl = *(const half8*)&Bsh[(wCol + j * 16) * 64 + aLoOff];
#pragma unroll
      for (int i = 0; i < 4; ++i)
        acc[i][j] = __builtin_amdgcn_mfma_f32_16x16x32_f16(ah[i], bl, acc[i][j], 0, 0, 0);
    }
    // phase 3: lo.hi — ah dead; stream al one tile at a time
#pragma unroll
    for (int i = 0; i < 4; ++i) {
      half8 al = *(const half8*)&Ash[(wRow + i * 16) * 64 + aLoOff];
#pragma unroll
      for (int j = 0; j < 4; ++j)
        acc[i][j] = __builtin_amdgcn_mfma_f32_16x16x32_f16(al, bh[j], acc[i][j], 0, 0, 0);
    }
  }

  // ---- epilogue: f = rq[col] - 2*dot, packed argmin ----
  // C/D layout (16x16): col = lane&15, row = (lane>>4)*4 + reg
  const int colBase = nBase + wCol + m16;
  float rqv[4];
#pragma unroll
  for (int j = 0; j < 4; ++j) rqv[j] = rq[colBase + j * 16];

#pragma unroll
  for (int i = 0; i < 4; ++i) {
    const int rowB = mBase + wRow + i * 16 + q * 4;
#pragma unroll
    for (int r = 0; r < 4; ++r) {
      unsigned long long pk = 0xFFFFFFFFFFFFFFFFULL;
#pragma unroll
      for (int j = 0; j < 4; ++j) {
        float f = fmaf(-2.0f, acc[i][j][r], rqv[j]);
        unsigned int bits = __float_as_uint(f);
        unsigned int key = (bits & 0x80000000u) ? ~bits : (bits | 0x80000000u);
        unsigned long long cand =
            ((unsigned long long)key << 32) | (unsigned)(colBase + j * 16);
        pk = pk < cand ? pk : cand;
      }
#pragma unroll
      for (int sft = 1; sft < 16; sft <<= 1) {
        unsigned long long o = __shfl_xor(pk, sft, 16);
        pk = pk < o ? pk : o;
      }
      if (m16 == 0) atomicMin(best + rowB + r, pk);
    }
  }
}

// ---------------------------- finalize ---------------------------------------
__global__ void finalize_kernel(const unsigned long long* __restrict__ best,
                                const float* __restrict__ rp,
                                float* __restrict__ out) {
  int i = blockIdx.x * 256 + threadIdx.x;
  if (i >= NPT) return;
  unsigned long long v = best[i];
  unsigned int col = (unsigned int)(v & 0xFFFFFFFFu);
  unsigned int key = (unsigned int)(v >> 32);
  unsigned int bits = (key & 0x80000000u) ? (key & 0x7FFFFFFFu) : ~key;
  float fmin = __uint_as_float(bits);
  out[i]           = (float)(col >> 7);   // idy
  out[NPT + i]     = (float)(col & 127);  // idx
  out[2 * NPT + i] = rp[i] + fmin;        // nnd
}

extern "C" void kernel_launch(void* const* d_in, const int* in_sizes, int n_in,
                              void* d_out, int out_size, void* d_ws, size_t ws_size,
                              hipStream_t stream) {
  const float* src = (const float*)d_in[0];  // source_map (1,32,128,128)
  const float* tgt = (const float*)d_in[1];  // target_map (1,32,128,128)
  float* out = (float*)d_out;

  // workspace layout (bytes):
  //   Aext: [0, 18874368)        16384 x 576 f16 (point-major [hi|lo])
  //   Bext: [18874368, 37748736)
  //   rq  : [37748736, 37814272) 16384 fp32 (target-side norms for the f-term)
  //   rp  : [37814272, 37879808)
  //   best: [37879808, 38010880) 16384 u64 packed (key<<32)|col
  char* ws = (char*)d_ws;
  f16* Aext = (f16*)(ws);
  f16* Bext = (f16*)(ws + 18874368);
  float* rq = (float*)(ws + 37748736);
  float* rp = (float*)(ws + 37814272);
  unsigned long long* best = (unsigned long long*)(ws + 37879808);

  extract_split_kernel<<<(NPT * 32) / 256, 256, 0, stream>>>(src, tgt, Aext, Bext,
                                                             rq, rp, best);
  {
    dim3 grid(128, 128);
    gemm_argmin_kernel<<<grid, 256, 0, stream>>>(Aext, Bext, rq, best);
  }
  finalize_kernel<<<NPT / 256, 256, 0, stream>>>(best, rp, out);
}